// Round 1
// baseline (184.147 us; speedup 1.0000x reference)
//
#include <hip/hip_runtime.h>
#include <hip/hip_bf16.h>

// Problem dims (fixed by setup_inputs)
#define B_DIM 4096   // tokens (C rows)
#define M_DIM 4096   // out_features (C cols, W rows)
#define K_DIM 4096   // in_features
#define NCODE 512    // Qidxs cols (K_DIM/8)

typedef __attribute__((ext_vector_type(4))) float f32x4;
typedef __attribute__((ext_vector_type(8))) short short8;

__device__ __forceinline__ unsigned short f2bf(float f) {
    union { float f; unsigned u; } c; c.f = f;
    unsigned u = c.u;
    return (unsigned short)((u + 0x7FFFu + ((u >> 16) & 1u)) >> 16);
}

// ---------------------------------------------------------------------------
// Kernel 1: dequantize codes -> bf16 W [M_DIM][K_DIM] row-major in ws
// one thread per code (2M threads); 16B coalesced stores; grid gathers hit L2
// ---------------------------------------------------------------------------
__global__ __launch_bounds__(256) void dequant_kernel(const int* __restrict__ Q,
                                                      const float* __restrict__ cb,
                                                      short* __restrict__ Wout) {
    const int t = blockIdx.x * 256 + threadIdx.x;   // 0 .. M_DIM*NCODE-1
    const int code = Q[t] & 0xFFFF;
    const float4* g = (const float4*)(cb + (size_t)code * 8);
    const float4 v0 = g[0];
    const float4 v1 = g[1];
    short8 o;
    o[0] = f2bf(v0.x); o[1] = f2bf(v0.y); o[2] = f2bf(v0.z); o[3] = f2bf(v0.w);
    o[4] = f2bf(v1.x); o[5] = f2bf(v1.y); o[6] = f2bf(v1.z); o[7] = f2bf(v1.w);
    *(short8*)(Wout + (size_t)t * 8) = o;
}

// ---------------------------------------------------------------------------
// Kernel 2: input fp32 -> bf16 (A matrix), 8 elems/thread
// ---------------------------------------------------------------------------
__global__ __launch_bounds__(256) void cvt_kernel(const float* __restrict__ in,
                                                  short* __restrict__ outb) {
    const int t = blockIdx.x * 256 + threadIdx.x;   // 0 .. B_DIM*K_DIM/8-1
    const float4* p = (const float4*)(in + (size_t)t * 8);
    const float4 v0 = p[0];
    const float4 v1 = p[1];
    short8 o;
    o[0] = f2bf(v0.x); o[1] = f2bf(v0.y); o[2] = f2bf(v0.z); o[3] = f2bf(v0.w);
    o[4] = f2bf(v1.x); o[5] = f2bf(v1.y); o[6] = f2bf(v1.z); o[7] = f2bf(v1.w);
    *(short8*)(outb + (size_t)t * 8) = o;
}

// ---------------------------------------------------------------------------
// Kernel 3: C[B,M] = A[B,K] * W[M,K]^T   (both bf16, fp32 accum)
// m97 structure: 128x128 tile, BK=64, 4 waves (2x2 of 64x64), global_load_lds
// width=16 staging, 2 barriers per K-step.
// LDS XOR swizzle (both-sides): logical (row, unit16B) stored at byte
//   row*128 + (unit ^ (row&7))*16. global_load_lds writes linearly, so the
//   SOURCE address is inverse-swizzled: lane l of chunk q fetches
//   row = q*8 + (l>>3), unit = (l&7) ^ (l>>3).
// ---------------------------------------------------------------------------
#define TM 128
#define TN 128
#define TK 64

__global__ __launch_bounds__(256) void gemm_bt_kernel(const short* __restrict__ A,
                                                      const short* __restrict__ Wd,
                                                      float* __restrict__ C) {
    __shared__ short laA[TM * TK];   // 16 KB
    __shared__ short laB[TN * TK];   // 16 KB

    const int tid  = threadIdx.x;
    const int wave = tid >> 6;
    const int lane = tid & 63;

    const int rowBase = blockIdx.y * TM;   // input-row tile
    const int colBase = blockIdx.x * TN;   // W-row tile

    const int wr = wave >> 1;   // 0..1  (64-row half)
    const int wc = wave & 1;    // 0..1  (64-col half)

    f32x4 acc[4][4] = {};

    // staging source (inverse-swizzled so swizzled reads see logical layout)
    const int srow  = lane >> 3;            // 0..7 within 8-row chunk
    const int sunit = (lane & 7) ^ srow;    // 16B unit within row
    const short* Abase = A  + (size_t)rowBase * K_DIM;
    const short* Bbase = Wd + (size_t)colBase * K_DIM;

    for (int k0 = 0; k0 < K_DIM; k0 += TK) {
        __syncthreads();   // previous compute done before overwrite
#pragma unroll
        for (int c = 0; c < 4; ++c) {
            const int q   = wave * 4 + c;           // chunk 0..15 (1 KiB each)
            const int row = q * 8 + srow;
            const size_t goff = (size_t)row * K_DIM + (size_t)(k0 + sunit * 8);
            __builtin_amdgcn_global_load_lds(
                (const __attribute__((address_space(1))) void*)(Abase + goff),
                (__attribute__((address_space(3))) void*)(&laA[q * 512]),
                16, 0, 0);
            __builtin_amdgcn_global_load_lds(
                (const __attribute__((address_space(1))) void*)(Bbase + goff),
                (__attribute__((address_space(3))) void*)(&laB[q * 512]),
                16, 0, 0);
        }
        __syncthreads();   // compiler drains vmcnt(0) before this barrier

#pragma unroll
        for (int kk = 0; kk < 2; ++kk) {
            short8 af[4], bf[4];
#pragma unroll
            for (int m = 0; m < 4; ++m) {
                const int r = wr * 64 + m * 16 + (lane & 15);
                const int u = (kk * 4 + (lane >> 4)) ^ (r & 7);
                af[m] = *(const short8*)&laA[r * TK + u * 8];
            }
#pragma unroll
            for (int n = 0; n < 4; ++n) {
                const int r = wc * 64 + n * 16 + (lane & 15);
                const int u = (kk * 4 + (lane >> 4)) ^ (r & 7);
                bf[n] = *(const short8*)&laB[r * TK + u * 8];
            }
#pragma unroll
            for (int m = 0; m < 4; ++m)
#pragma unroll
                for (int n = 0; n < 4; ++n)
                    acc[m][n] = __builtin_amdgcn_mfma_f32_16x16x32_bf16(
                        af[m], bf[n], acc[m][n], 0, 0, 0);
        }
    }

    // epilogue: C/D layout col = lane&15, row = (lane>>4)*4 + reg
    const int lrow = (lane >> 4) * 4;
    const int lcol = lane & 15;
    const int r0 = rowBase + wr * 64 + lrow;
    const int c0 = colBase + wc * 64 + lcol;
#pragma unroll
    for (int m = 0; m < 4; ++m)
#pragma unroll
        for (int n = 0; n < 4; ++n) {
            float* cp = C + (size_t)(r0 + m * 16) * M_DIM + (c0 + n * 16);
#pragma unroll
            for (int reg = 0; reg < 4; ++reg)
                cp[(size_t)reg * M_DIM] = acc[m][n][reg];
        }
}

// ---------------------------------------------------------------------------
extern "C" void kernel_launch(void* const* d_in, const int* in_sizes, int n_in,
                              void* d_out, int out_size, void* d_ws, size_t ws_size,
                              hipStream_t stream) {
    const float* inp  = (const float*)d_in[0];   // [B_DIM, K_DIM] fp32
    const int*   qidx = (const int*)d_in[1];     // [M_DIM, NCODE] int32
    const float* cb   = (const float*)d_in[2];   // [65536, 8] fp32
    float* out = (float*)d_out;                  // [B_DIM, M_DIM] fp32

    // workspace layout: W bf16 (32 MB) | A bf16 (32 MB)
    short* Wb = (short*)d_ws;
    short* Ab = Wb + (size_t)M_DIM * K_DIM;

    const int n_codes = M_DIM * NCODE;           // 2,097,152
    dequant_kernel<<<n_codes / 256, 256, 0, stream>>>(qidx, cb, Wb);

    const int n_cvt = B_DIM * K_DIM / 8;         // 2,097,152
    cvt_kernel<<<n_cvt / 256, 256, 0, stream>>>(inp, Ab);

    dim3 grid(M_DIM / TN, B_DIM / TM);           // 32 x 32
    gemm_bt_kernel<<<grid, 256, 0, stream>>>(Ab, Wb, out);
}

// Round 3
// 156.283 us; speedup vs baseline: 1.1783x; 1.1783x over previous
//
#include <hip/hip_runtime.h>
#include <hip/hip_bf16.h>

#define B_DIM 4096
#define M_DIM 4096
#define K_DIM 4096
#define NCODE 512

typedef __attribute__((ext_vector_type(4))) float f32x4;
typedef __attribute__((ext_vector_type(8))) short short8;

__device__ __forceinline__ unsigned short f2bf(float f) {
    union { float f; unsigned u; } c; c.f = f;
    unsigned u = c.u;
    return (unsigned short)((u + 0x7FFFu + ((u >> 16) & 1u)) >> 16);
}

// ---------------------------------------------------------------------------
// Kernel 1: dequantize codes -> bf16 W [M_DIM][K_DIM] row-major in ws
// ---------------------------------------------------------------------------
__global__ __launch_bounds__(256) void dequant_kernel(const int* __restrict__ Q,
                                                      const float* __restrict__ cb,
                                                      short* __restrict__ Wout) {
    const int t = blockIdx.x * 256 + threadIdx.x;
    const int code = Q[t] & 0xFFFF;
    const float4* g = (const float4*)(cb + (size_t)code * 8);
    const float4 v0 = g[0];
    const float4 v1 = g[1];
    short8 o;
    o[0] = f2bf(v0.x); o[1] = f2bf(v0.y); o[2] = f2bf(v0.z); o[3] = f2bf(v0.w);
    o[4] = f2bf(v1.x); o[5] = f2bf(v1.y); o[6] = f2bf(v1.z); o[7] = f2bf(v1.w);
    *(short8*)(Wout + (size_t)t * 8) = o;
}

// ---------------------------------------------------------------------------
// Kernel 2: input fp32 -> bf16
// ---------------------------------------------------------------------------
__global__ __launch_bounds__(256) void cvt_kernel(const float* __restrict__ in,
                                                  short* __restrict__ outb) {
    const int t = blockIdx.x * 256 + threadIdx.x;
    const float4* p = (const float4*)(in + (size_t)t * 8);
    const float4 v0 = p[0];
    const float4 v1 = p[1];
    short8 o;
    o[0] = f2bf(v0.x); o[1] = f2bf(v0.y); o[2] = f2bf(v0.z); o[3] = f2bf(v0.w);
    o[4] = f2bf(v1.x); o[5] = f2bf(v1.y); o[6] = f2bf(v1.z); o[7] = f2bf(v1.w);
    *(short8*)(outb + (size_t)t * 8) = o;
}

// ---------------------------------------------------------------------------
// Kernel 3: C[B,M] = A[B,K] * W[M,K]^T  — 256x256 tile, BK=32, 8 waves (2x4),
// 4-deep LDS ring, stage tile t+3 while computing tile t, counted vmcnt(6),
// 2 phases/iter each {ds_reads || 2 gload_lds -> barrier -> 16 MFMA -> barrier}.
// Pipeline proof: iter t's vmcnt(6)+barrier drains all threads' loads through
// tile t+1, so iter t+1's ds_reads (after that barrier) are safe. Tile 0 is
// covered by the post-prologue vmcnt(8)+barrier (drains tile 0's 4 loads).
// ---------------------------------------------------------------------------
#define BM 256
#define BN 256
#define BK 32
#define NT (K_DIM / BK)   // 128

#define GLD(src, dst) \
    __builtin_amdgcn_global_load_lds( \
        (const __attribute__((address_space(1))) void*)(src), \
        (__attribute__((address_space(3))) void*)(dst), 16, 0, 0)

__global__ __launch_bounds__(512, 2) void gemm_bt_kernel(const short* __restrict__ A,
                                                         const short* __restrict__ Wd,
                                                         float* __restrict__ C) {
    // 4 ring buffers x (A: 8192 shorts | B: 8192 shorts) = 128 KB
    __shared__ short lds[4 * 16384];

    const int tid  = threadIdx.x;
    const int wave = tid >> 6;
    const int lane = tid & 63;

    // XCD-chunked swizzle: 256 blocks -> 8 XCDs, each a 4x8 block chunk
    const int bid = blockIdx.x;
    const int xcd = bid & 7;
    const int s   = bid >> 3;                 // 0..31 within chunk
    const int by  = (xcd >> 1) * 4 + (s >> 3);
    const int bx  = (xcd & 1) * 8 + (s & 7);

    const int rowBase = by * BM;
    const int colBase = bx * BN;

    const int wr = wave >> 2;                 // 0..1  (128-row half)
    const int wc = wave & 3;                  // 0..3  (64-col quarter)

    // stage sources: thread covers slots tid (rows 0..127) and tid+512 (128..255)
    const int u   = tid & 3;                  // 16B unit within 64B row
    const int rA0 = tid >> 2;
    const short* aSrc0 = A  + (size_t)(rowBase + rA0) * K_DIM + u * 8;
    const short* aSrc1 = A  + (size_t)(rowBase + rA0 + 128) * K_DIM + u * 8;
    const short* bSrc0 = Wd + (size_t)(colBase + rA0) * K_DIM + u * 8;
    const short* bSrc1 = Wd + (size_t)(colBase + rA0 + 128) * K_DIM + u * 8;

    // ds_read per-lane base offsets (shorts); frag m adds m*512, frag n adds n*512
    const int l15 = lane & 15;
    const int l4  = lane >> 4;
    const int aRd = (wr * 128 + l15) * 32 + l4 * 8;
    const int bRd = 8192 + (wc * 64 + l15) * 32 + l4 * 8;

    f32x4 acc[8][4] = {};

    // prologue: stage tiles 0,1,2 (12 gloads/thread in flight)
#pragma unroll
    for (int p = 0; p < 3; ++p) {
        const int koff = p * BK;
        short* base = &lds[p * 16384];
        GLD(aSrc0 + koff, base + wave * 512);
        GLD(aSrc1 + koff, base + 4096 + wave * 512);
        GLD(bSrc0 + koff, base + 8192 + wave * 512);
        GLD(bSrc1 + koff, base + 12288 + wave * 512);
    }
    // Tile 0 must be workgroup-visible before iter 0's ds_reads:
    // drain the 4 oldest loads (= tile 0), leave tiles 1,2 in flight.
    asm volatile("s_waitcnt vmcnt(8)" ::: "memory");
    __builtin_amdgcn_s_barrier();

    for (int t = 0; t < NT; ++t) {
        const int buf    = (t & 3) * 16384;
        const int tpre   = (t + 3 < NT) ? (t + 3) : (NT - 1);
        const int kpre   = tpre * BK;
        const int bufpre = ((t + 3) & 3) * 16384;

        // ---------------- Phase 0: quadrant m0-3 x n0-3 ----------------
        short8 af0[4], bf[4];
#pragma unroll
        for (int m = 0; m < 4; ++m)
            af0[m] = *(const short8*)&lds[buf + aRd + m * 512];
#pragma unroll
        for (int n = 0; n < 4; ++n)
            bf[n] = *(const short8*)&lds[buf + bRd + n * 512];
        GLD(aSrc0 + kpre, &lds[bufpre + wave * 512]);
        GLD(aSrc1 + kpre, &lds[bufpre + 4096 + wave * 512]);
        asm volatile("s_waitcnt vmcnt(6)" ::: "memory");  // tile t+1 fully landed
        __builtin_amdgcn_s_barrier();
        __builtin_amdgcn_s_setprio(1);
#pragma unroll
        for (int m = 0; m < 4; ++m)
#pragma unroll
            for (int n = 0; n < 4; ++n)
                acc[m][n] = __builtin_amdgcn_mfma_f32_16x16x32_bf16(
                    af0[m], bf[n], acc[m][n], 0, 0, 0);
        __builtin_amdgcn_s_setprio(0);
        __builtin_amdgcn_s_barrier();

        // ---------------- Phase 1: quadrant m4-7 x n0-3 ----------------
        short8 af1[4];
#pragma unroll
        for (int m = 0; m < 4; ++m)
            af1[m] = *(const short8*)&lds[buf + aRd + (m + 4) * 512];
        GLD(bSrc0 + kpre, &lds[bufpre + 8192 + wave * 512]);
        GLD(bSrc1 + kpre, &lds[bufpre + 12288 + wave * 512]);
        __builtin_amdgcn_s_barrier();
        __builtin_amdgcn_s_setprio(1);
#pragma unroll
        for (int m = 0; m < 4; ++m)
#pragma unroll
            for (int n = 0; n < 4; ++n)
                acc[m + 4][n] = __builtin_amdgcn_mfma_f32_16x16x32_bf16(
                    af1[m], bf[n], acc[m + 4][n], 0, 0, 0);
        __builtin_amdgcn_s_setprio(0);
        __builtin_amdgcn_s_barrier();
    }

    // epilogue: C/D layout col = lane&15, row = (lane>>4)*4 + reg
    const int r0 = rowBase + wr * 128 + l4 * 4;
    const int c0 = colBase + wc * 64 + l15;
#pragma unroll
    for (int m = 0; m < 8; ++m)
#pragma unroll
        for (int n = 0; n < 4; ++n) {
            float* cp = C + (size_t)(r0 + m * 16) * M_DIM + (c0 + n * 16);
#pragma unroll
            for (int reg = 0; reg < 4; ++reg)
                cp[(size_t)reg * M_DIM] = acc[m][n][reg];
        }
}

// ---------------------------------------------------------------------------
extern "C" void kernel_launch(void* const* d_in, const int* in_sizes, int n_in,
                              void* d_out, int out_size, void* d_ws, size_t ws_size,
                              hipStream_t stream) {
    const float* inp  = (const float*)d_in[0];
    const int*   qidx = (const int*)d_in[1];
    const float* cb   = (const float*)d_in[2];
    float* out = (float*)d_out;

    short* Wb = (short*)d_ws;
    short* Ab = Wb + (size_t)M_DIM * K_DIM;

    const int n_codes = M_DIM * NCODE;
    dequant_kernel<<<n_codes / 256, 256, 0, stream>>>(qidx, cb, Wb);

    const int n_cvt = B_DIM * K_DIM / 8;
    cvt_kernel<<<n_cvt / 256, 256, 0, stream>>>(inp, Ab);

    gemm_bt_kernel<<<256, 512, 0, stream>>>(Ab, Wb, out);
}

// Round 4
// 149.296 us; speedup vs baseline: 1.2334x; 1.0468x over previous
//
#include <hip/hip_runtime.h>
#include <hip/hip_bf16.h>

#define B_DIM 4096
#define M_DIM 4096
#define K_DIM 4096
#define NCODE 512

typedef __attribute__((ext_vector_type(4))) float f32x4;
typedef __attribute__((ext_vector_type(8))) short short8;

__device__ __forceinline__ unsigned short f2bf(float f) {
    union { float f; unsigned u; } c; c.f = f;
    unsigned u = c.u;
    return (unsigned short)((u + 0x7FFFu + ((u >> 16) & 1u)) >> 16);
}

// ---------------------------------------------------------------------------
// Kernel 1: dequantize codes -> bf16 W [M_DIM][K_DIM] row-major in ws
// ---------------------------------------------------------------------------
__global__ __launch_bounds__(256) void dequant_kernel(const int* __restrict__ Q,
                                                      const float* __restrict__ cb,
                                                      short* __restrict__ Wout) {
    const int t = blockIdx.x * 256 + threadIdx.x;
    const int code = Q[t] & 0xFFFF;
    const float4* g = (const float4*)(cb + (size_t)code * 8);
    const float4 v0 = g[0];
    const float4 v1 = g[1];
    short8 o;
    o[0] = f2bf(v0.x); o[1] = f2bf(v0.y); o[2] = f2bf(v0.z); o[3] = f2bf(v0.w);
    o[4] = f2bf(v1.x); o[5] = f2bf(v1.y); o[6] = f2bf(v1.z); o[7] = f2bf(v1.w);
    *(short8*)(Wout + (size_t)t * 8) = o;
}

// ---------------------------------------------------------------------------
// Kernel 2: input fp32 -> bf16
// ---------------------------------------------------------------------------
__global__ __launch_bounds__(256) void cvt_kernel(const float* __restrict__ in,
                                                  short* __restrict__ outb) {
    const int t = blockIdx.x * 256 + threadIdx.x;
    const float4* p = (const float4*)(in + (size_t)t * 8);
    const float4 v0 = p[0];
    const float4 v1 = p[1];
    short8 o;
    o[0] = f2bf(v0.x); o[1] = f2bf(v0.y); o[2] = f2bf(v0.z); o[3] = f2bf(v0.w);
    o[4] = f2bf(v1.x); o[5] = f2bf(v1.y); o[6] = f2bf(v1.z); o[7] = f2bf(v1.w);
    *(short8*)(outb + (size_t)t * 8) = o;
}

// ---------------------------------------------------------------------------
// Kernel 3: C[B,M] = A[B,K] * W[M,K]^T  — 256x256 tile, BK=32, 8 waves (2x4),
// 4-deep LDS ring, stage tile t+3 while computing tile t, counted vmcnt(6).
// LDS unit-swizzle: logical (row, u) stored at unit su = u ^ ((row>>1)&3)
// => bank-group (4*row + su) % 8 covers all 8 groups twice per 16 rows:
// conflict-free ds_read_b128. global_load_lds writes linearly, so the GLOBAL
// source is inverse-swizzled (same involution, both-sides rule).
// Pipeline proof: iter t's vmcnt(6)+barrier drains all threads' loads through
// tile t+1, so iter t+1's ds_reads (after that barrier) are safe. Tile 0 is
// covered by the post-prologue vmcnt(8)+barrier (drains tile 0's 4 loads).
// ---------------------------------------------------------------------------
#define BM 256
#define BN 256
#define BK 32
#define NT (K_DIM / BK)   // 128

#define GLD(src, dst) \
    __builtin_amdgcn_global_load_lds( \
        (const __attribute__((address_space(1))) void*)(src), \
        (__attribute__((address_space(3))) void*)(dst), 16, 0, 0)

__global__ __launch_bounds__(512, 2) void gemm_bt_kernel(const short* __restrict__ A,
                                                         const short* __restrict__ Wd,
                                                         float* __restrict__ C) {
    // 4 ring buffers x (A: 8192 shorts | B: 8192 shorts) = 128 KB
    __shared__ short lds[4 * 16384];

    const int tid  = threadIdx.x;
    const int wave = tid >> 6;
    const int lane = tid & 63;

    // XCD-chunked swizzle: 256 blocks -> 8 XCDs, each a 4x8 block chunk
    const int bid = blockIdx.x;
    const int xcd = bid & 7;
    const int s   = bid >> 3;                 // 0..31 within chunk
    const int by  = (xcd >> 1) * 4 + (s >> 3);
    const int bx  = (xcd & 1) * 8 + (s & 7);

    const int rowBase = by * BM;
    const int colBase = bx * BN;

    const int wr = wave >> 2;                 // 0..1  (128-row half)
    const int wc = wave & 3;                  // 0..3  (64-col quarter)

    // stage sources: inverse-swizzled unit so swizzled reads see logical data.
    // lane covers row rA0 = tid>>2, stored-unit tid&3; logical unit is XOR'd.
    const int rA0 = tid >> 2;
    const int uu  = (tid & 3) ^ ((rA0 >> 1) & 3);
    const short* aSrc0 = A  + (size_t)(rowBase + rA0) * K_DIM + uu * 8;
    const short* aSrc1 = A  + (size_t)(rowBase + rA0 + 128) * K_DIM + uu * 8;
    const short* bSrc0 = Wd + (size_t)(colBase + rA0) * K_DIM + uu * 8;
    const short* bSrc1 = Wd + (size_t)(colBase + rA0 + 128) * K_DIM + uu * 8;

    // ds_read per-lane base offsets (shorts); frag m adds m*512, n adds n*512.
    // fragment row = base16 + l15 -> (row>>1)&3 == (l15>>1)&3 for all frags.
    const int l15 = lane & 15;
    const int l4  = lane >> 4;
    const int sx  = (l15 >> 1) & 3;
    const int aRd = (wr * 128 + l15) * 32 + (l4 ^ sx) * 8;
    const int bRd = 8192 + (wc * 64 + l15) * 32 + (l4 ^ sx) * 8;

    f32x4 acc[8][4] = {};

    // prologue: stage tiles 0,1,2 (12 gloads/thread in flight)
#pragma unroll
    for (int p = 0; p < 3; ++p) {
        const int koff = p * BK;
        short* base = &lds[p * 16384];
        GLD(aSrc0 + koff, base + wave * 512);
        GLD(aSrc1 + koff, base + 4096 + wave * 512);
        GLD(bSrc0 + koff, base + 8192 + wave * 512);
        GLD(bSrc1 + koff, base + 12288 + wave * 512);
    }
    // Tile 0 must be workgroup-visible before iter 0's ds_reads:
    // drain the 4 oldest loads (= tile 0), leave tiles 1,2 in flight.
    asm volatile("s_waitcnt vmcnt(8)" ::: "memory");
    __builtin_amdgcn_s_barrier();

    for (int t = 0; t < NT; ++t) {
        const int buf    = (t & 3) * 16384;
        const int tpre   = (t + 3 < NT) ? (t + 3) : (NT - 1);
        const int kpre   = tpre * BK;
        const int bufpre = ((t + 3) & 3) * 16384;

        // ---------------- Phase 0: quadrant m0-3 x n0-3 ----------------
        short8 af0[4], bf[4];
#pragma unroll
        for (int m = 0; m < 4; ++m)
            af0[m] = *(const short8*)&lds[buf + aRd + m * 512];
#pragma unroll
        for (int n = 0; n < 4; ++n)
            bf[n] = *(const short8*)&lds[buf + bRd + n * 512];
        GLD(aSrc0 + kpre, &lds[bufpre + wave * 512]);
        GLD(aSrc1 + kpre, &lds[bufpre + 4096 + wave * 512]);
        asm volatile("s_waitcnt vmcnt(6)" ::: "memory");  // tile t+1 fully landed
        __builtin_amdgcn_s_barrier();
        __builtin_amdgcn_s_setprio(1);
#pragma unroll
        for (int m = 0; m < 4; ++m)
#pragma unroll
            for (int n = 0; n < 4; ++n)
                acc[m][n] = __builtin_amdgcn_mfma_f32_16x16x32_bf16(
                    af0[m], bf[n], acc[m][n], 0, 0, 0);
        __builtin_amdgcn_s_setprio(0);
        __builtin_amdgcn_s_barrier();

        // ---------------- Phase 1: quadrant m4-7 x n0-3 ----------------
        short8 af1[4];
#pragma unroll
        for (int m = 0; m < 4; ++m)
            af1[m] = *(const short8*)&lds[buf + aRd + (m + 4) * 512];
        GLD(bSrc0 + kpre, &lds[bufpre + 8192 + wave * 512]);
        GLD(bSrc1 + kpre, &lds[bufpre + 12288 + wave * 512]);
        __builtin_amdgcn_s_barrier();
        __builtin_amdgcn_s_setprio(1);
#pragma unroll
        for (int m = 0; m < 4; ++m)
#pragma unroll
            for (int n = 0; n < 4; ++n)
                acc[m + 4][n] = __builtin_amdgcn_mfma_f32_16x16x32_bf16(
                    af1[m], bf[n], acc[m + 4][n], 0, 0, 0);
        __builtin_amdgcn_s_setprio(0);
        __builtin_amdgcn_s_barrier();
    }

    // epilogue: C/D layout col = lane&15, row = (lane>>4)*4 + reg
    const int r0 = rowBase + wr * 128 + l4 * 4;
    const int c0 = colBase + wc * 64 + l15;
#pragma unroll
    for (int m = 0; m < 8; ++m)
#pragma unroll
        for (int n = 0; n < 4; ++n) {
            float* cp = C + (size_t)(r0 + m * 16) * M_DIM + (c0 + n * 16);
#pragma unroll
            for (int reg = 0; reg < 4; ++reg)
                cp[(size_t)reg * M_DIM] = acc[m][n][reg];
        }
}

// ---------------------------------------------------------------------------
extern "C" void kernel_launch(void* const* d_in, const int* in_sizes, int n_in,
                              void* d_out, int out_size, void* d_ws, size_t ws_size,
                              hipStream_t stream) {
    const float* inp  = (const float*)d_in[0];
    const int*   qidx = (const int*)d_in[1];
    const float* cb   = (const float*)d_in[2];
    float* out = (float*)d_out;

    short* Wb = (short*)d_ws;
    short* Ab = Wb + (size_t)M_DIM * K_DIM;

    const int n_codes = M_DIM * NCODE;
    dequant_kernel<<<n_codes / 256, 256, 0, stream>>>(qidx, cb, Wb);

    const int n_cvt = B_DIM * K_DIM / 8;
    cvt_kernel<<<n_cvt / 256, 256, 0, stream>>>(inp, Ab);

    gemm_bt_kernel<<<256, 512, 0, stream>>>(Ab, Wb, out);
}

// Round 5
// 141.891 us; speedup vs baseline: 1.2978x; 1.0522x over previous
//
#include <hip/hip_runtime.h>
#include <hip/hip_bf16.h>

#define B_DIM 4096
#define M_DIM 4096
#define K_DIM 4096
#define NCODE 512

typedef __attribute__((ext_vector_type(4))) float f32x4;
typedef __attribute__((ext_vector_type(8))) short short8;

__device__ __forceinline__ unsigned short f2bf(float f) {
    union { float f; unsigned u; } c; c.f = f;
    unsigned u = c.u;
    return (unsigned short)((u + 0x7FFFu + ((u >> 16) & 1u)) >> 16);
}

// ---------------------------------------------------------------------------
// Kernel 1: dequantize codes -> bf16 W [M_DIM][K_DIM] row-major in ws
// ---------------------------------------------------------------------------
__global__ __launch_bounds__(256) void dequant_kernel(const int* __restrict__ Q,
                                                      const float* __restrict__ cb,
                                                      short* __restrict__ Wout) {
    const int t = blockIdx.x * 256 + threadIdx.x;
    const int code = Q[t] & 0xFFFF;
    const float4* g = (const float4*)(cb + (size_t)code * 8);
    const float4 v0 = g[0];
    const float4 v1 = g[1];
    short8 o;
    o[0] = f2bf(v0.x); o[1] = f2bf(v0.y); o[2] = f2bf(v0.z); o[3] = f2bf(v0.w);
    o[4] = f2bf(v1.x); o[5] = f2bf(v1.y); o[6] = f2bf(v1.z); o[7] = f2bf(v1.w);
    *(short8*)(Wout + (size_t)t * 8) = o;
}

// ---------------------------------------------------------------------------
// Kernel 2: input fp32 -> bf16
// ---------------------------------------------------------------------------
__global__ __launch_bounds__(256) void cvt_kernel(const float* __restrict__ in,
                                                  short* __restrict__ outb) {
    const int t = blockIdx.x * 256 + threadIdx.x;
    const float4* p = (const float4*)(in + (size_t)t * 8);
    const float4 v0 = p[0];
    const float4 v1 = p[1];
    short8 o;
    o[0] = f2bf(v0.x); o[1] = f2bf(v0.y); o[2] = f2bf(v0.z); o[3] = f2bf(v0.w);
    o[4] = f2bf(v1.x); o[5] = f2bf(v1.y); o[6] = f2bf(v1.z); o[7] = f2bf(v1.w);
    *(short8*)(outb + (size_t)t * 8) = o;
}

// ---------------------------------------------------------------------------
// Kernel 3: C[B,M] = A[B,K] * W[M,K]^T — 256x256 tile, BK=32, 8 waves (2x4),
// 4-deep LDS ring + REGISTER-LEVEL PHASE PIPELINE:
//   ph0: read a1 (tile t, m4-7)        -> feeds ph1's MFMA
//        GLD A(t+3); vmcnt(6); B1; MFMA acc[0..3] (frags read last iter ph1)
//   ph1: GLD B(t+3); lgkmcnt(0); B2;
//        read aNxt/bNxt (tile t+1)     -> feeds next iter's ph0 MFMA
//        MFMA acc[4..7] (a1 x bCur)
// Every ds_read drains during an MFMA burst -> LDS/MFMA pipes overlap.
// Hazard proof:
//  - staging visibility: vmcnt(6) at ph0 drains all waves' GLDs through tile
//    t+1; B1 makes it workgroup-wide. Tile t+1 reads happen after B2 > B1. OK
//  - overwrite: GLD into buf(x) for tile x+4 is issued at iter x+1 ph0, i.e.
//    after B2(x). All reads of buf(x) (a1 at iter x ph0; aNxt/bNxt at iter
//    x-1 ph1) are drained by the explicit lgkmcnt(0) before B2(x). OK
//  - tile 0: post-prologue vmcnt(8)+barrier before the prologue frag reads.
// Loop unrolled x2 for static frag-register naming (no scratch).
// LDS unit-swizzle (conflict-free, both-sides): stored unit = u^((row>>1)&3).
// ---------------------------------------------------------------------------
#define BM 256
#define BN 256
#define BK 32
#define NT (K_DIM / BK)   // 128

#define GLD(src, dst) \
    __builtin_amdgcn_global_load_lds( \
        (const __attribute__((address_space(1))) void*)(src), \
        (__attribute__((address_space(3))) void*)(dst), 16, 0, 0)

#define MFMA(a, b, c) __builtin_amdgcn_mfma_f32_16x16x32_bf16(a, b, c, 0, 0, 0)

__global__ __launch_bounds__(512, 2) void gemm_bt_kernel(const short* __restrict__ A,
                                                         const short* __restrict__ Wd,
                                                         float* __restrict__ C) {
    __shared__ short lds[4 * 16384];   // 4 ring buffers x (A 16KB | B 16KB)

    const int tid  = threadIdx.x;
    const int wave = tid >> 6;
    const int lane = tid & 63;

    // XCD-chunked swizzle: 256 blocks -> 8 XCDs, each a 4x8 block chunk
    const int bid = blockIdx.x;
    const int xcd = bid & 7;
    const int s   = bid >> 3;
    const int by  = (xcd >> 1) * 4 + (s >> 3);
    const int bx  = (xcd & 1) * 8 + (s & 7);

    const int rowBase = by * BM;
    const int colBase = bx * BN;

    const int wr = wave >> 2;                 // 0..1  (128-row half)
    const int wc = wave & 3;                  // 0..3  (64-col quarter)

    // stage sources (inverse-swizzled unit)
    const int rA0 = tid >> 2;
    const int uu  = (tid & 3) ^ ((rA0 >> 1) & 3);
    const short* aSrc0 = A  + (size_t)(rowBase + rA0) * K_DIM + uu * 8;
    const short* aSrc1 = A  + (size_t)(rowBase + rA0 + 128) * K_DIM + uu * 8;
    const short* bSrc0 = Wd + (size_t)(colBase + rA0) * K_DIM + uu * 8;
    const short* bSrc1 = Wd + (size_t)(colBase + rA0 + 128) * K_DIM + uu * 8;

    // ds_read per-lane base offsets (shorts); frag f adds f*512
    const int l15 = lane & 15;
    const int l4  = lane >> 4;
    const int sx  = (l15 >> 1) & 3;
    const int aRd = (wr * 128 + l15) * 32 + (l4 ^ sx) * 8;
    const int bRd = 8192 + (wc * 64 + l15) * 32 + (l4 ^ sx) * 8;

    f32x4 acc[8][4] = {};
    short8 aX[4], bX[4], aY[4], bY[4], a1[4];

    // prologue: stage tiles 0,1,2
#pragma unroll
    for (int p = 0; p < 3; ++p) {
        const int koff = p * BK;
        short* base = &lds[p * 16384];
        GLD(aSrc0 + koff, base + wave * 512);
        GLD(aSrc1 + koff, base + 4096 + wave * 512);
        GLD(bSrc0 + koff, base + 8192 + wave * 512);
        GLD(bSrc1 + koff, base + 12288 + wave * 512);
    }
    asm volatile("s_waitcnt vmcnt(8)" ::: "memory");   // tile 0 landed
    __builtin_amdgcn_s_barrier();
#pragma unroll
    for (int m = 0; m < 4; ++m) aX[m] = *(const short8*)&lds[aRd + m * 512];
#pragma unroll
    for (int n = 0; n < 4; ++n) bX[n] = *(const short8*)&lds[bRd + n * 512];

#define ITER_BODY(T, AC, BC, AN, BN)                                          \
    {                                                                         \
        const int buf    = ((T) & 3) * 16384;                                 \
        const int bufn   = (((T) + 1) & 3) * 16384;                           \
        const int tpre   = ((T) + 3 < NT) ? ((T) + 3) : (NT - 1);             \
        const int kpre   = tpre * BK;                                         \
        const int bufpre = (((T) + 3) & 3) * 16384;                           \
        _Pragma("unroll")                                                     \
        for (int m = 0; m < 4; ++m)                                           \
            a1[m] = *(const short8*)&lds[buf + aRd + (m + 4) * 512];          \
        GLD(aSrc0 + kpre, &lds[bufpre + wave * 512]);                         \
        GLD(aSrc1 + kpre, &lds[bufpre + 4096 + wave * 512]);                  \
        asm volatile("s_waitcnt vmcnt(6)" ::: "memory");                      \
        __builtin_amdgcn_s_barrier();                                         \
        __builtin_amdgcn_s_setprio(1);                                        \
        _Pragma("unroll")                                                     \
        for (int m = 0; m < 4; ++m)                                           \
            _Pragma("unroll")                                                 \
            for (int n = 0; n < 4; ++n)                                       \
                acc[m][n] = MFMA(AC[m], BC[n], acc[m][n]);                    \
        __builtin_amdgcn_s_setprio(0);                                        \
        GLD(bSrc0 + kpre, &lds[bufpre + 8192 + wave * 512]);                  \
        GLD(bSrc1 + kpre, &lds[bufpre + 12288 + wave * 512]);                 \
        asm volatile("s_waitcnt lgkmcnt(0)" ::: "memory");                    \
        __builtin_amdgcn_s_barrier();                                         \
        _Pragma("unroll")                                                     \
        for (int m = 0; m < 4; ++m)                                           \
            AN[m] = *(const short8*)&lds[bufn + aRd + m * 512];               \
        _Pragma("unroll")                                                     \
        for (int n = 0; n < 4; ++n)                                           \
            BN[n] = *(const short8*)&lds[bufn + bRd + n * 512];               \
        __builtin_amdgcn_s_setprio(1);                                        \
        _Pragma("unroll")                                                     \
        for (int m = 0; m < 4; ++m)                                           \
            _Pragma("unroll")                                                 \
            for (int n = 0; n < 4; ++n)                                       \
                acc[m + 4][n] = MFMA(a1[m], BC[n], acc[m + 4][n]);            \
        __builtin_amdgcn_s_setprio(0);                                        \
    }

    for (int t2 = 0; t2 < NT; t2 += 2) {
        ITER_BODY(t2,     aX, bX, aY, bY)
        ITER_BODY(t2 + 1, aY, bY, aX, bX)
    }
#undef ITER_BODY

    // epilogue: C/D layout col = lane&15, row = (lane>>4)*4 + reg
    const int r0 = rowBase + wr * 128 + l4 * 4;
    const int c0 = colBase + wc * 64 + l15;
#pragma unroll
    for (int m = 0; m < 8; ++m)
#pragma unroll
        for (int n = 0; n < 4; ++n) {
            float* cp = C + (size_t)(r0 + m * 16) * M_DIM + (c0 + n * 16);
#pragma unroll
            for (int reg = 0; reg < 4; ++reg)
                cp[(size_t)reg * M_DIM] = acc[m][n][reg];
        }
}

// ---------------------------------------------------------------------------
extern "C" void kernel_launch(void* const* d_in, const int* in_sizes, int n_in,
                              void* d_out, int out_size, void* d_ws, size_t ws_size,
                              hipStream_t stream) {
    const float* inp  = (const float*)d_in[0];
    const int*   qidx = (const int*)d_in[1];
    const float* cb   = (const float*)d_in[2];
    float* out = (float*)d_out;

    short* Wb = (short*)d_ws;
    short* Ab = Wb + (size_t)M_DIM * K_DIM;

    const int n_codes = M_DIM * NCODE;
    dequant_kernel<<<n_codes / 256, 256, 0, stream>>>(qidx, cb, Wb);

    const int n_cvt = B_DIM * K_DIM / 8;
    cvt_kernel<<<n_cvt / 256, 256, 0, stream>>>(inp, Ab);

    gemm_bt_kernel<<<256, 512, 0, stream>>>(Ab, Wb, out);
}